// Round 1
// baseline (4835.856 us; speedup 1.0000x reference)
//
#include <hip/hip_runtime.h>
#include <cmath>
#include <cstdint>

#define NT 256
#define MAX_ROUNDS 48
#define SCAN_T 32
#define SCAN_IPB (NT*SCAN_T)   // 8192 items per scan block

// ---------------- MIS loop kernels ----------------

__global__ void k_init_rank(int* mr, int* tmp, int n){
  int v = blockIdx.x*NT + threadIdx.x;
  if(v<n){ mr[v]=v; tmp[v]=v; }
}

__global__ void k_copy(int* dst, const int* src, int n, const int* cnt, int round){
  if(round>0 && cnt[round-1]==0) return;
  int v = blockIdx.x*NT + threadIdx.x;
  if(v<n) dst[v]=src[v];
}

// dst must equal src on entry; computes dst[v] = min(src[v], min over in-edges src[row])
__global__ void k_scat_min(int* dst, const int* src, const int* row, const int* col,
                           int E, const int* cnt, int round){
  if(round>0 && cnt[round-1]==0) return;
  int stride = gridDim.x*NT;
  for(int e = blockIdx.x*NT + threadIdx.x; e<E; e+=stride){
    atomicMin(&dst[col[e]], src[row[e]]);
  }
}

// dst must equal src on entry; dst[col] |= src[row]  (write of constant 1, no atomic needed)
__global__ void k_scat_or(int* dst, const int* src, const int* row, const int* col,
                          int E, const int* cnt, int round){
  if(round>0 && cnt[round-1]==0) return;
  int stride = gridDim.x*NT;
  for(int e = blockIdx.x*NT + threadIdx.x; e<E; e+=stride){
    if(src[row[e]]) dst[col[e]] = 1;
  }
}

__global__ void k_mis_update(const int* mr, int* mis, int* maskA, int* maskB,
                             int n, const int* cnt, int round){
  if(round>0 && cnt[round-1]==0) return;
  int v = blockIdx.x*NT + threadIdx.x;
  if(v<n){
    int m = mis[v] | (mr[v]==v);   // rank(v) == v
    mis[v]=m; maskA[v]=m; maskB[v]=m;
  }
}

__global__ void k_finalize(const int* maskA, int* mr, int* tmp, int n, int* cnt, int round){
  if(round>0 && cnt[round-1]==0) return;
  int v = blockIdx.x*NT + threadIdx.x;
  int unc = 0;
  if(v<n){
    int cov = maskA[v];
    int r = cov ? n : v;
    mr[v]=r; tmp[v]=r;
    unc = cov ? 0 : 1;
  }
  __shared__ int sh[NT];
  sh[threadIdx.x]=unc; __syncthreads();
  for(int off=NT/2; off>0; off>>=1){
    if(threadIdx.x<off) sh[threadIdx.x]+=sh[threadIdx.x+off];
    __syncthreads();
  }
  if(threadIdx.x==0 && sh[0]) atomicAdd(&cnt[round], sh[0]);
}

// ---------------- cluster phase ----------------

__global__ void k_cluster_init(const int* mis, int* mr, int* tmp, int n){
  int v = blockIdx.x*NT + threadIdx.x;
  if(v<n){ int m = mis[v] ? v : n; mr[v]=m; tmp[v]=m; }
}

__global__ void k_mark(const int* mr, const int* mis, int* present, int* cmis, int n){
  int v = blockIdx.x*NT + threadIdx.x;
  int m = 0;
  if(v<n){
    int r = mr[v];
    if(r<n) present[r]=1;
    m = mis[v];
  }
  __shared__ int sh[NT];
  sh[threadIdx.x]=m; __syncthreads();
  for(int off=NT/2; off>0; off>>=1){
    if(threadIdx.x<off) sh[threadIdx.x]+=sh[threadIdx.x+off];
    __syncthreads();
  }
  if(threadIdx.x==0 && sh[0]) atomicAdd(cmis, sh[0]);
}

// ---------------- generic 3-pass exclusive scan over int array ----------------

__global__ void k_scan1(const int* A, int M, int* bsum){
  int t = threadIdx.x;
  long base = (long)blockIdx.x*SCAN_IPB + (long)t*SCAN_T;
  int s = 0;
  #pragma unroll
  for(int j=0;j<SCAN_T;j++){ long i=base+j; if(i<M) s += A[i]; }
  __shared__ int sh[NT];
  sh[t]=s; __syncthreads();
  for(int off=NT/2; off>0; off>>=1){ if(t<off) sh[t]+=sh[t+off]; __syncthreads(); }
  if(t==0) bsum[blockIdx.x]=sh[0];
}

__global__ void k_scan2(const int* bsum, int* bscan, int B, int* totalOut){
  __shared__ int sh[NT];
  int t = threadIdx.x;
  int carry = 0;
  for(int base=0; base<B; base+=NT){
    int i = base+t;
    int v = (i<B) ? bsum[i] : 0;
    sh[t]=v; __syncthreads();
    for(int off=1; off<NT; off<<=1){
      int x=0; if(t>=off) x=sh[t-off];
      __syncthreads();
      sh[t]+=x; __syncthreads();
    }
    int incl = sh[t];
    if(i<B) bscan[i] = carry + incl - v;   // exclusive
    carry += sh[NT-1];
    __syncthreads();
  }
  if(t==0 && totalOut) *totalOut = carry;
}

__global__ void k_scan3(const int* A, int M, const int* bscan, int* pref){
  int t = threadIdx.x;
  long base = (long)blockIdx.x*SCAN_IPB + (long)t*SCAN_T;
  int s = 0;
  #pragma unroll
  for(int j=0;j<SCAN_T;j++){ long i=base+j; if(i<M) s += A[i]; }
  __shared__ int sh[NT];
  sh[t]=s; __syncthreads();
  for(int off=1; off<NT; off<<=1){
    int x=0; if(t>=off) x=sh[t-off];
    __syncthreads();
    sh[t]+=x; __syncthreads();
  }
  int run = bscan[blockIdx.x] + (sh[t]-s);
  for(int j=0;j<SCAN_T;j++){
    long i=base+j;
    if(i<M){ pref[i]=run; run += A[i]; }
  }
}

// ---------------- clustering & pooling ----------------

__global__ void k_assign(const int* mr, const int* pref, int* cl, int* ccount, int n){
  int v = blockIdx.x*NT + threadIdx.x;
  if(v<n){
    int r = mr[v];
    int cid = (r<n) ? pref[r] : 0;
    cl[v]=cid;
    atomicAdd(&ccount[cid],1);
  }
}

__global__ void k_scatter_nodes(const int* cl, const int* cstart, int* cursor, int* nodeList, int n){
  int v = blockIdx.x*NT + threadIdx.x;
  if(v<n){
    int cid = cl[v];
    int pos = cstart[cid] + atomicAdd(&cursor[cid],1);
    nodeList[pos]=v;
  }
}

// one block per cluster; thread t = feature dim t (D==256==blockDim)
__global__ void k_pool_x(const float* __restrict__ x, const int* nodeList, const int* cstart,
                         const int* ccount, const int* scal, float* out, long out_size){
  int c = scal[0], U = scal[1];
  int t = threadIdx.x;
  for(int cid=blockIdx.x; cid<c; cid+=gridDim.x){
    float s = 0.f;
    if(cid<U){
      int st = cstart[cid], cn = ccount[cid];
      for(int i=0;i<cn;i++){
        int nd = nodeList[st+i];
        s += x[(size_t)nd*256 + t];
      }
    }
    long idx = (long)cid*256 + t;
    if(idx < out_size) out[idx]=s;
  }
}

__global__ void k_edge_pool(const int* row, const int* col, const float* attr, const int* cl,
                            const int* scal, float* dense, unsigned int* bits, int E, long CMsq){
  int c = scal[0];
  int stride = gridDim.x*NT;
  for(int e = blockIdx.x*NT + threadIdx.x; e<E; e+=stride){
    long key = (long)cl[row[e]]*c + cl[col[e]];
    if(key < CMsq){
      atomicAdd(&dense[key], attr[e]);
      atomicOr(&bits[key>>5], 1u<<((int)key&31));
    }
  }
}

__device__ __forceinline__ int cell_pred(long k, int c, const unsigned int* bits){
  if(!((bits[k>>5]>>((int)k&31))&1u)) return 0;
  int r = (int)(k/c), q = (int)(k - (long)r*c);
  return r!=q;   // remove self-loops
}

__global__ void k_cscan1(const unsigned int* bits, const int* scal, int* bsum, long CMsq){
  int c = scal[0];
  long M = (long)c*c; if(M>CMsq) M=CMsq;
  int t = threadIdx.x;
  long base = (long)blockIdx.x*SCAN_IPB + (long)t*SCAN_T;
  int s = 0;
  for(int j=0;j<SCAN_T;j++){ long i=base+j; if(i<M) s += cell_pred(i,c,bits); }
  __shared__ int sh[NT];
  sh[t]=s; __syncthreads();
  for(int off=NT/2; off>0; off>>=1){ if(t<off) sh[t]+=sh[t+off]; __syncthreads(); }
  if(t==0) bsum[blockIdx.x]=sh[0];
}

__global__ void k_cemit(const unsigned int* bits, const float* dense, const int* scal,
                        const int* bscan, float* out, long out_size, long CMsq){
  int c = scal[0]; int P = scal[2];
  long M = (long)c*c; if(M>CMsq) M=CMsq;
  long xoff = (long)c*256;
  int t = threadIdx.x;
  long base = (long)blockIdx.x*SCAN_IPB + (long)t*SCAN_T;
  int s = 0;
  for(int j=0;j<SCAN_T;j++){ long i=base+j; if(i<M) s += cell_pred(i,c,bits); }
  __shared__ int sh[NT];
  sh[t]=s; __syncthreads();
  for(int off=1; off<NT; off<<=1){
    int x=0; if(t>=off) x=sh[t-off];
    __syncthreads();
    sh[t]+=x; __syncthreads();
  }
  int run = bscan[blockIdx.x] + (sh[t]-s);
  for(int j=0;j<SCAN_T;j++){
    long i=base+j;
    if(i<M && cell_pred(i,c,bits)){
      int r=(int)(i/c), q=(int)(i-(long)r*c);
      long o0 = xoff + run;
      long o1 = xoff + (long)P + run;
      long o2 = xoff + 2L*(long)P + run;
      if(o0<out_size) out[o0]=(float)r;
      if(o1<out_size) out[o1]=(float)q;
      if(o2<out_size) out[o2]=dense[i];
      run++;
    }
  }
}

// ---------------- host ----------------

extern "C" void kernel_launch(void* const* d_in, const int* in_sizes, int n_in,
                              void* d_out, int out_size, void* d_ws, size_t ws_size,
                              hipStream_t stream){
  (void)n_in;
  const float* x     = (const float*)d_in[0];
  const int*   eidx  = (const int*)d_in[1];
  const float* eattr = (const float*)d_in[2];
  const int D = 256;
  int n = in_sizes[0]/D;
  int E = in_sizes[1]/2;
  const int* row = eidx;
  const int* col = eidx + E;

  // ---- workspace layout (256B-aligned bump allocator) ----
  char* p = (char*)d_ws;
  auto alloc = [&](size_t bytes)->char*{ char* r=p; p += (bytes+255)&~(size_t)255; return r; };
  int* mr    = (int*)alloc((size_t)n*4);
  int* tmp   = (int*)alloc((size_t)n*4);
  int* maskA = (int*)alloc((size_t)n*4);   // reused as nodeList
  int* maskB = (int*)alloc((size_t)n*4);   // reused as cl
  int* pref  = (int*)alloc((size_t)n*4);   // reused as clusterStart
  int* bsum  = (int*)alloc(4096*4);
  int* bscan = (int*)alloc(4096*4);
  char* zstart = p;                         // everything below is zeroed each call
  int* mis     = (int*)alloc((size_t)n*4);
  int* present = (int*)alloc((size_t)n*4);
  int* ccount  = (int*)alloc((size_t)n*4);
  int* cursor  = (int*)alloc((size_t)n*4);
  int* cnt     = (int*)alloc(MAX_ROUNDS*4);
  int* scal    = (int*)alloc(64);           // [0]=c (mis count), [1]=U (#unique), [2]=P (#pooled edges)

  size_t used   = (size_t)(p-(char*)d_ws);
  size_t remain = (ws_size > used+4096) ? ws_size-used-4096 : 0;
  size_t cells  = remain/5;                 // dense f32 (4B) + bitmask (0.125B) + slack
  long CM = (long)std::sqrt((double)cells);
  while(CM>1 && CM*CM > (long)cells) CM--;
  if(CM>4096) CM=4096;
  if(CM<1) CM=1;
  long CMsq = CM*CM;
  unsigned int* bits = (unsigned int*)alloc(((size_t)CMsq/32 + 2)*4);
  float* dense       = (float*)alloc((size_t)CMsq*4);
  size_t zbytes = (size_t)(p - zstart);
  hipMemsetAsync(zstart, 0, zbytes, stream);

  int NB  = (n+NT-1)/NT;
  int EB  = 1024;
  int NBs = (n+SCAN_IPB-1)/SCAN_IPB;
  int CB  = (int)((CMsq+SCAN_IPB-1)/SCAN_IPB);

  // ---- Luby-style k-MIS (k=2), unrolled with early-exit on convergence ----
  k_init_rank<<<NB,NT,0,stream>>>(mr,tmp,n);
  for(int r=0;r<MAX_ROUNDS;r++){
    k_scat_min<<<EB,NT,0,stream>>>(tmp,mr,row,col,E,cnt,r);   // hop 1 (tmp==mr on entry)
    k_copy    <<<NB,NT,0,stream>>>(mr,tmp,n,cnt,r);
    k_scat_min<<<EB,NT,0,stream>>>(mr,tmp,row,col,E,cnt,r);   // hop 2
    k_mis_update<<<NB,NT,0,stream>>>(mr,mis,maskA,maskB,n,cnt,r);
    k_scat_or <<<EB,NT,0,stream>>>(maskB,maskA,row,col,E,cnt,r); // dilate hop 1
    k_copy    <<<NB,NT,0,stream>>>(maskA,maskB,n,cnt,r);
    k_scat_or <<<EB,NT,0,stream>>>(maskA,maskB,row,col,E,cnt,r); // dilate hop 2
    k_finalize<<<NB,NT,0,stream>>>(maskA,mr,tmp,n,cnt,r);        // reset min_rank, count uncovered
  }

  // ---- cluster assignment: min_rank = mis? rank : n, propagate 2 hops ----
  k_cluster_init<<<NB,NT,0,stream>>>(mis,mr,tmp,n);
  k_scat_min<<<EB,NT,0,stream>>>(tmp,mr,row,col,E,cnt,0);
  k_copy    <<<NB,NT,0,stream>>>(mr,tmp,n,cnt,0);
  k_scat_min<<<EB,NT,0,stream>>>(mr,tmp,row,col,E,cnt,0);

  // ---- unique(min_rank) -> dense cluster ids (sorted order) ----
  k_mark <<<NB,NT,0,stream>>>(mr,mis,present,scal,n);     // also counts c = sum(mis)
  k_scan1<<<NBs,NT,0,stream>>>(present,n,bsum);
  k_scan2<<<1,NT,0,stream>>>(bsum,bscan,NBs,scal+1);      // U = #unique
  k_scan3<<<NBs,NT,0,stream>>>(present,n,bscan,pref);
  k_assign<<<NB,NT,0,stream>>>(mr,pref,maskB/*cl*/,ccount,n);

  // ---- counting sort nodes by cluster (for x_pooled) ----
  k_scan1<<<NBs,NT,0,stream>>>(ccount,n,bsum);
  k_scan2<<<1,NT,0,stream>>>(bsum,bscan,NBs,nullptr);
  k_scan3<<<NBs,NT,0,stream>>>(ccount,n,bscan,pref/*clusterStart*/);
  k_scatter_nodes<<<NB,NT,0,stream>>>(maskB,pref,cursor,maskA/*nodeList*/,n);

  // ---- x_pooled = segment_sum(x, cluster, c) ----
  k_pool_x<<<1024,NT,0,stream>>>(x,maskA,pref,ccount,scal,(float*)d_out,(long)out_size);

  // ---- pooled adjacency: dense c x c accumulate, then sorted compaction ----
  k_edge_pool<<<EB,NT,0,stream>>>(row,col,eattr,maskB,scal,dense,bits,E,CMsq);
  k_cscan1<<<CB,NT,0,stream>>>(bits,scal,bsum,CMsq);
  k_scan2 <<<1,NT,0,stream>>>(bsum,bscan,CB,scal+2);      // P = #kept pooled edges
  k_cemit <<<CB,NT,0,stream>>>(bits,dense,scal,bscan,(float*)d_out,(long)out_size,CMsq);
}